// Round 4
// baseline (646.572 us; speedup 1.0000x reference)
//
#include <hip/hip_runtime.h>
#include <hip/hip_bf16.h>
#include <math.h>

#define NN 50000
#define NE 500000
#define KSEL 25000

typedef unsigned int u32;
typedef unsigned long long u64;

// ---------------- small precompute kernels ----------------

// Wqk[k][m] = sum_c Wq[c,k]*Wk[c,m]  -> BigW cols 0:128 ; also bqk
__global__ __launch_bounds__(128) void k_wqk(const float* __restrict__ Wq, const float* __restrict__ Wk,
                                             const float* __restrict__ bq,
                                             float* __restrict__ BigW, float* __restrict__ bqk) {
    int k = blockIdx.x;   // 0..127
    int m = threadIdx.x;  // 0..127
    float acc = 0.f;
    for (int c = 0; c < 128; ++c) acc += Wq[c * 128 + k] * Wk[c * 128 + m];
    BigW[k * 384 + m] = acc;
    if (k == 0) {
        float b = 0.f;
        for (int c = 0; c < 128; ++c) b += bq[c] * Wk[c * 128 + m];
        bqk[m] = b;
    }
}

// BigW cols 128:384 (W0a|W1a), B2 (W0b^T|W1b^T), small vectors
// wvecs: wa0[0:128] wa1[128:256] wb0[256:384] wb1[384:512] wkn[512:640] bkbq[640]
__global__ void k_prep(const float* __restrict__ Wb, const float* __restrict__ Wq,
                       const float* __restrict__ bq, const float* __restrict__ bk,
                       const float* __restrict__ Wv,
                       float* __restrict__ BigW, float* __restrict__ B2, float* __restrict__ wvecs) {
    int idx = blockIdx.x * blockDim.x + threadIdx.x;
    const int T1 = 128 * 256, T2 = 128 * 256;
    if (idx < T1) {
        int k = idx >> 8, t = idx & 255;
        float v = (t < 128) ? Wb[k * 128 + t] : Wb[256 * 128 + k * 128 + (t - 128)];
        BigW[k * 384 + 128 + t] = v;
    } else if (idx < T1 + T2) {
        int i = idx - T1;
        int m = i >> 8, t = i & 255;
        int base = (t < 128) ? 0 : 256 * 128;
        int kk = (t < 128) ? t : t - 128;
        B2[m * 256 + t] = Wb[base + (128 + kk) * 128 + m];
    } else {
        int i = idx - T1 - T2;
        if (i < 128)      { float s = 0; for (int m = 0; m < 128; ++m) s += Wb[i * 128 + m] * Wv[m]; wvecs[i] = s; }
        else if (i < 256) { int j = i - 128; float s = 0; for (int m = 0; m < 128; ++m) s += Wb[256 * 128 + j * 128 + m] * Wv[m]; wvecs[i] = s; }
        else if (i < 384) { int j = i - 256; float s = 0; for (int m = 0; m < 128; ++m) s += Wb[(128 + j) * 128 + m] * Wv[m]; wvecs[i] = s; }
        else if (i < 512) { int j = i - 384; float s = 0; for (int m = 0; m < 128; ++m) s += Wb[256 * 128 + (128 + j) * 128 + m] * Wv[m]; wvecs[i] = s; }
        else if (i < 640) { int j = i - 512; float s = 0; for (int c = 0; c < 128; ++c) s += bk[c] * Wq[c * 128 + j]; wvecs[i] = s; }
        else if (i == 640) { float s = 0; for (int c = 0; c < 128; ++c) s += bk[c] * bq[c]; wvecs[640] = s; }
    }
}

// ---------------- node GEMMs (f32 vector, 128x128 tile, 256 thr, 8x8 micro) ----------------

// C[j, 0:128 of col-tile ct] = h @ BigW[:, ct*128 : ...]; ct=0 adds bqk -> q2; ct=1 -> a0; ct=2 -> a1
__global__ __launch_bounds__(256) void k_gemm1(const float* __restrict__ h, const float* __restrict__ BigW,
                                               const float* __restrict__ bqk,
                                               float* __restrict__ q2, float* __restrict__ a0f, float* __restrict__ a1f) {
    __shared__ float As[16][132];
    __shared__ float Bs[16][132];
    int t = threadIdx.x;
    int mb = blockIdx.x * 128;
    int ct = blockIdx.y;
    int colbase = ct * 128;
    int tr = t >> 4, tc = t & 15;
    float acc[8][8];
#pragma unroll
    for (int i = 0; i < 8; ++i)
#pragma unroll
        for (int j = 0; j < 8; ++j) acc[i][j] = 0.f;

    int anode = t >> 1, ahalf = t & 1;
    int arow = mb + anode;
    bool avalid = arow < NN;
    const float* aptr = h + (size_t)arow * 128 + ahalf * 8;
    int bkk = t >> 4, bcg = t & 15;
    const float* bptr = BigW + (size_t)bkk * 384 + colbase + bcg * 8;

    float4 av0, av1, bv0, bv1;
    av0 = avalid ? *(const float4*)(aptr) : make_float4(0, 0, 0, 0);
    av1 = avalid ? *(const float4*)(aptr + 4) : make_float4(0, 0, 0, 0);
    bv0 = *(const float4*)(bptr);
    bv1 = *(const float4*)(bptr + 4);

    for (int ks = 0; ks < 8; ++ks) {
        __syncthreads();
        {
            float a[8] = {av0.x, av0.y, av0.z, av0.w, av1.x, av1.y, av1.z, av1.w};
#pragma unroll
            for (int q = 0; q < 8; ++q) As[ahalf * 8 + q][anode] = a[q];
            *(float4*)&Bs[bkk][bcg * 8] = bv0;
            *(float4*)&Bs[bkk][bcg * 8 + 4] = bv1;
        }
        __syncthreads();
        if (ks < 7) {
            const float* ap = aptr + (ks + 1) * 16;
            av0 = avalid ? *(const float4*)(ap) : make_float4(0, 0, 0, 0);
            av1 = avalid ? *(const float4*)(ap + 4) : make_float4(0, 0, 0, 0);
            const float* bp = bptr + (size_t)(ks + 1) * 16 * 384;
            bv0 = *(const float4*)(bp);
            bv1 = *(const float4*)(bp + 4);
        }
#pragma unroll
        for (int kk = 0; kk < 16; ++kk) {
            float4 aA = *(const float4*)&As[kk][tr * 8];
            float4 aB = *(const float4*)&As[kk][tr * 8 + 4];
            float4 bA = *(const float4*)&Bs[kk][tc * 8];
            float4 bB = *(const float4*)&Bs[kk][tc * 8 + 4];
            float a8[8] = {aA.x, aA.y, aA.z, aA.w, aB.x, aB.y, aB.z, aB.w};
            float b8[8] = {bA.x, bA.y, bA.z, bA.w, bB.x, bB.y, bB.z, bB.w};
#pragma unroll
            for (int i = 0; i < 8; ++i)
#pragma unroll
                for (int j = 0; j < 8; ++j) acc[i][j] += a8[i] * b8[j];
        }
    }
    float* dst = (ct == 0) ? q2 : (ct == 1) ? a0f : a1f;
#pragma unroll
    for (int i = 0; i < 8; ++i) {
        int row = mb + tr * 8 + i;
        if (row < NN) {
            float o[8];
#pragma unroll
            for (int j = 0; j < 8; ++j) {
                float v = acc[i][j];
                if (ct == 0) v += bqk[tc * 8 + j];
                o[j] = v;
            }
            *(float4*)(dst + (size_t)row * 128 + tc * 8) = make_float4(o[0], o[1], o[2], o[3]);
            *(float4*)(dst + (size_t)row * 128 + tc * 8 + 4) = make_float4(o[4], o[5], o[6], o[7]);
        }
    }
}

// u = q2 @ B2[:, which*128:...] ; t{which}[j] = sum_k u[j,k]*h[j,k]  -> TT[j*4+which]
__global__ __launch_bounds__(256) void k_gemm2(const float* __restrict__ q2, const float* __restrict__ B2,
                                               const float* __restrict__ h, float* __restrict__ TT) {
    __shared__ float As[16][132];
    __shared__ float Bs[16][132];
    __shared__ float tpart[128];
    int t = threadIdx.x;
    int mb = blockIdx.x * 128;
    int which = blockIdx.y;
    int colbase = which * 128;
    int tr = t >> 4, tc = t & 15;
    if (t < 128) tpart[t] = 0.f;
    float acc[8][8];
#pragma unroll
    for (int i = 0; i < 8; ++i)
#pragma unroll
        for (int j = 0; j < 8; ++j) acc[i][j] = 0.f;

    int anode = t >> 1, ahalf = t & 1;
    int arow = mb + anode;
    bool avalid = arow < NN;
    const float* aptr = q2 + (size_t)arow * 128 + ahalf * 8;
    int bkk = t >> 4, bcg = t & 15;
    const float* bptr = B2 + (size_t)bkk * 256 + colbase + bcg * 8;

    float4 av0, av1, bv0, bv1;
    av0 = avalid ? *(const float4*)(aptr) : make_float4(0, 0, 0, 0);
    av1 = avalid ? *(const float4*)(aptr + 4) : make_float4(0, 0, 0, 0);
    bv0 = *(const float4*)(bptr);
    bv1 = *(const float4*)(bptr + 4);

    for (int ks = 0; ks < 8; ++ks) {
        __syncthreads();
        {
            float a[8] = {av0.x, av0.y, av0.z, av0.w, av1.x, av1.y, av1.z, av1.w};
#pragma unroll
            for (int q = 0; q < 8; ++q) As[ahalf * 8 + q][anode] = a[q];
            *(float4*)&Bs[bkk][bcg * 8] = bv0;
            *(float4*)&Bs[bkk][bcg * 8 + 4] = bv1;
        }
        __syncthreads();
        if (ks < 7) {
            const float* ap = aptr + (ks + 1) * 16;
            av0 = avalid ? *(const float4*)(ap) : make_float4(0, 0, 0, 0);
            av1 = avalid ? *(const float4*)(ap + 4) : make_float4(0, 0, 0, 0);
            const float* bp = bptr + (size_t)(ks + 1) * 16 * 256;
            bv0 = *(const float4*)(bp);
            bv1 = *(const float4*)(bp + 4);
        }
#pragma unroll
        for (int kk = 0; kk < 16; ++kk) {
            float4 aA = *(const float4*)&As[kk][tr * 8];
            float4 aB = *(const float4*)&As[kk][tr * 8 + 4];
            float4 bA = *(const float4*)&Bs[kk][tc * 8];
            float4 bB = *(const float4*)&Bs[kk][tc * 8 + 4];
            float a8[8] = {aA.x, aA.y, aA.z, aA.w, aB.x, aB.y, aB.z, aB.w};
            float b8[8] = {bA.x, bA.y, bA.z, bA.w, bB.x, bB.y, bB.z, bB.w};
#pragma unroll
            for (int i = 0; i < 8; ++i)
#pragma unroll
                for (int j = 0; j < 8; ++j) acc[i][j] += a8[i] * b8[j];
        }
    }
#pragma unroll
    for (int i = 0; i < 8; ++i) {
        int row = mb + tr * 8 + i;
        if (row < NN) {
            float4 hA = *(const float4*)(h + (size_t)row * 128 + tc * 8);
            float4 hB = *(const float4*)(h + (size_t)row * 128 + tc * 8 + 4);
            float p = acc[i][0] * hA.x + acc[i][1] * hA.y + acc[i][2] * hA.z + acc[i][3] * hA.w +
                      acc[i][4] * hB.x + acc[i][5] * hB.y + acc[i][6] * hB.z + acc[i][7] * hB.w;
            atomicAdd(&tpart[tr * 8 + i], p);
        }
    }
    __syncthreads();
    if (t < 128) {
        int row = mb + t;
        if (row < NN) TT[(size_t)row * 4 + which] = tpart[t];
    }
}

// per-node scalars: av0,av1,bv0,bv1 (NS), kn (TT.z), self_y
__global__ void k_scal(const float* __restrict__ h, const float* __restrict__ wvecs,
                       const float* __restrict__ coeff, const float* __restrict__ bvp,
                       float* __restrict__ NS, float* __restrict__ TT, float* __restrict__ selfy) {
    int gid = blockIdx.x * blockDim.x + threadIdx.x;
    int wid = gid >> 6, lane = gid & 63;
    if (wid >= NN) return;
    const float* hrow = h + (size_t)wid * 128;
    float2 hv = *(const float2*)(hrow + lane * 2);
    float2 w0 = *(const float2*)(wvecs + 0 + lane * 2);
    float2 w1 = *(const float2*)(wvecs + 128 + lane * 2);
    float2 w2 = *(const float2*)(wvecs + 256 + lane * 2);
    float2 w3 = *(const float2*)(wvecs + 384 + lane * 2);
    float2 w4 = *(const float2*)(wvecs + 512 + lane * 2);
    float p0 = hv.x * w0.x + hv.y * w0.y;
    float p1 = hv.x * w1.x + hv.y * w1.y;
    float p2 = hv.x * w2.x + hv.y * w2.y;
    float p3 = hv.x * w3.x + hv.y * w3.y;
    float p4 = hv.x * w4.x + hv.y * w4.y;
    for (int off = 32; off; off >>= 1) {
        p0 += __shfl_xor(p0, off);
        p1 += __shfl_xor(p1, off);
        p2 += __shfl_xor(p2, off);
        p3 += __shfl_xor(p3, off);
        p4 += __shfl_xor(p4, off);
    }
    if (lane == 0) {
        float kn = p4 + wvecs[640];
        float c40 = coeff[8], c41 = coeff[9], bv = bvp[0];
        NS[(size_t)wid * 4 + 0] = p0;
        NS[(size_t)wid * 4 + 1] = p1;
        NS[(size_t)wid * 4 + 2] = p2;
        NS[(size_t)wid * 4 + 3] = p3;
        TT[(size_t)wid * 4 + 2] = kn;
        selfy[wid] = c40 * (p0 + p2) + c41 * (p1 + p3) + bv;
    }
}

// ---------------- edge kernel: 1 wave = 1 edge, 4x 16-lane dot groups ----------------
__global__ __launch_bounds__(256) void k_edge(const float* __restrict__ a0f, const float* __restrict__ a1f,
                                              const float* __restrict__ q2,
                                              const int* __restrict__ src, const int* __restrict__ dst,
                                              const int* __restrict__ et,
                                              const float* __restrict__ NS, const float* __restrict__ TT,
                                              const float* __restrict__ coeff, const float* __restrict__ bvp,
                                              float* __restrict__ acc) {
    int gid = blockIdx.x * blockDim.x + threadIdx.x;
    int e = gid >> 6;
    if (e >= NE) return;
    int lane = threadIdx.x & 63;
    int s = src[e], d = dst[e];
    int g = lane >> 4, sub = lane & 15;
    const float* A = (g & 1) ? a1f : a0f;
    int r1 = (g < 2) ? s : d;
    int r2 = (g < 2) ? d : s;
    const float* ap = A + (size_t)r1 * 128 + sub * 8;
    const float* qp = q2 + (size_t)r2 * 128 + sub * 8;
    float4 x0 = *(const float4*)ap, x1 = *(const float4*)(ap + 4);
    float4 y0 = *(const float4*)qp, y1 = *(const float4*)(qp + 4);
    float p = x0.x * y0.x + x0.y * y0.y + x0.z * y0.z + x0.w * y0.w +
              x1.x * y1.x + x1.y * y1.y + x1.z * y1.z + x1.w * y1.w;
    p += __shfl_xor(p, 8);
    p += __shfl_xor(p, 4);
    p += __shfl_xor(p, 2);
    p += __shfl_xor(p, 1);
    float d0i = __shfl(p, 0), d1i = __shfl(p, 16), d0o = __shfl(p, 32), d1o = __shfl(p, 48);
    if (lane == 0 || lane == 32) {
        bool outdir = (lane == 32);
        int agg = outdir ? s : d;
        int oth = outdir ? d : s;
        float dd0 = outdir ? d0o : d0i;
        float dd1 = outdir ? d1o : d1i;
        int ety = et[e];
        float c0 = coeff[ety * 2], c1 = coeff[ety * 2 + 1];
        float t0 = TT[(size_t)agg * 4 + 0], t1 = TT[(size_t)agg * 4 + 1], kn = TT[(size_t)agg * 4 + 2];
        float av0 = NS[(size_t)oth * 4 + 0], av1 = NS[(size_t)oth * 4 + 1];
        float bv0 = NS[(size_t)agg * 4 + 2], bv1 = NS[(size_t)agg * 4 + 3];
        float raw = c0 * (dd0 + t0) + c1 * (dd1 + t1) + kn;
        float xc = fminf(fmaxf(raw * 0.08838834764831845f, -10.f), 10.f);
        float sc = expf(xc);
        float nv = c0 * (av0 + bv0) + c1 * (av1 + bv1) + bvp[0];
        float* wacc = acc + (size_t)(outdir ? 2 : 0) * NN;
        float* zacc = acc + (size_t)(outdir ? 3 : 1) * NN;
        atomicAdd(&wacc[agg], sc * nv);
        atomicAdd(&zacc[agg], sc);
    }
}

// ---------------- y, key, ranking, selection, output ----------------

__global__ void k_y(const float* __restrict__ acc, const float* __restrict__ selfy,
                    float* __restrict__ y, u32* __restrict__ key, u32* __restrict__ hist) {
    int i = blockIdx.x * blockDim.x + threadIdx.x;
    if (i >= NN) return;
    float win = acc[i], zin = acc[NN + i], wout = acc[2 * NN + i], zout = acc[3 * NN + i];
    float v = win / (zin + 1e-6f) + wout / (zout + 1e-6f) + selfy[i];
    y[i] = v;
    u32 u = __float_as_uint(v);
    u32 m = (u32)((int)u >> 31) | 0x80000000u;
    u32 k = ~(u ^ m);  // ascending k == descending y
    key[i] = k;
    atomicAdd(&hist[k >> 16], 1u);
}

__global__ __launch_bounds__(1024) void k_scan(const u32* __restrict__ hist, u32* __restrict__ P) {
    __shared__ u32 wsum[16];
    __shared__ u32 woff[16];
    int t = threadIdx.x;
    int base = t * 64;
    u32 s = 0;
    for (int i = 0; i < 64; ++i) s += hist[base + i];
    u32 v = s;
    int lane = t & 63;
    for (int off = 1; off < 64; off <<= 1) {
        u32 n = __shfl_up(v, off);
        if (lane >= off) v += n;
    }
    int wid = t >> 6;
    if (lane == 63) wsum[wid] = v;
    __syncthreads();
    if (t == 0) {
        u32 r = 0;
        for (int w = 0; w < 16; ++w) { woff[w] = r; r += wsum[w]; }
    }
    __syncthreads();
    u32 excl = v - s + woff[wid];
    for (int i = 0; i < 64; ++i) { P[base + i] = excl; excl += hist[base + i]; }
    if (t == 1023) P[65536] = excl;
}

__global__ void k_scatter(const u32* __restrict__ key, const u32* __restrict__ P,
                          u32* __restrict__ cnt, u64* __restrict__ S) {
    int i = blockIdx.x * blockDim.x + threadIdx.x;
    if (i >= NN) return;
    u32 k = key[i];
    u32 b = k >> 16;
    u32 pos = P[b] + atomicAdd(&cnt[b], 1u);
    S[pos] = ((u64)k << 16) | (u32)i;
}

__global__ void k_rank(const u32* __restrict__ key, const u32* __restrict__ P,
                       const u64* __restrict__ S, u32* __restrict__ rnk) {
    int i = blockIdx.x * blockDim.x + threadIdx.x;
    if (i >= NN) return;
    u32 k = key[i];
    u32 b = k >> 16;
    u64 me = ((u64)k << 16) | (u32)i;
    u32 st = P[b], en = P[b + 1];
    u32 c = 0;
    for (u32 j = st; j < en; ++j) c += (S[j] < me) ? 1u : 0u;
    rnk[i] = st + c;
}

__global__ void k_bsum(const u32* __restrict__ rnk, u32* __restrict__ bs) {
    __shared__ u32 red[4];
    int i = blockIdx.x * 256 + threadIdx.x;
    u32 v = (i < NN && rnk[i] < KSEL) ? 1u : 0u;
    for (int off = 32; off; off >>= 1) v += __shfl_xor(v, off);
    int lane = threadIdx.x & 63, w = threadIdx.x >> 6;
    if (lane == 0) red[w] = v;
    __syncthreads();
    if (threadIdx.x == 0) bs[blockIdx.x] = red[0] + red[1] + red[2] + red[3];
}

__global__ void k_bscan(const u32* __restrict__ bs, u32* __restrict__ bo, int nb) {
    if (threadIdx.x == 0) {
        u32 r = 0;
        for (int i = 0; i < nb; ++i) { bo[i] = r; r += bs[i]; }
    }
}

__global__ void k_select(const u32* __restrict__ rnk, const u32* __restrict__ bo,
                         u32* __restrict__ selj, float* __restrict__ out_ids) {
    __shared__ u32 woff[4];
    int t = threadIdx.x;
    int i = blockIdx.x * 256 + t;
    u32 f = (i < NN && rnk[i] < KSEL) ? 1u : 0u;
    u32 v = f;
    int lane = t & 63;
    for (int off = 1; off < 64; off <<= 1) {
        u32 n = __shfl_up(v, off);
        if (lane >= off) v += n;
    }
    int w = t >> 6;
    if (lane == 63) woff[w] = v;
    __syncthreads();
    if (t == 0) {
        u32 r = 0;
        for (int k = 0; k < 4; ++k) { u32 x = woff[k]; woff[k] = r; r += x; }
    }
    __syncthreads();
    if (f) {
        u32 r = bo[blockIdx.x] + woff[w] + (v - f);
        selj[r] = rnk[i];
        out_ids[r] = (float)i;
    }
}

__global__ void k_rows(const u32* __restrict__ selj, const float* __restrict__ h,
                       const float* __restrict__ y, float* __restrict__ out) {
    int row = blockIdx.x * 2 + (threadIdx.x >> 7);
    int c = threadIdx.x & 127;
    if (row >= KSEL) return;
    u32 j = selj[row];
    float yv = y[j];
    float sig = 1.f / (1.f + expf(-yv));
    float v = h[(size_t)j * 128 + c] * sig;
    out[(size_t)row * 128 + c] = v;
}

// ---------------- launcher ----------------

extern "C" void kernel_launch(void* const* d_in, const int* in_sizes, int n_in,
                              void* d_out, int out_size, void* d_ws, size_t ws_size,
                              hipStream_t stream) {
    const float* h    = (const float*)d_in[0];
    const int* src    = (const int*)d_in[1];
    const int* dstp   = (const int*)d_in[2];
    const int* etype  = (const int*)d_in[3];
    const float* Wb   = (const float*)d_in[4];
    const float* coeff = (const float*)d_in[5];
    const float* Wq   = (const float*)d_in[6];
    const float* bq   = (const float*)d_in[7];
    const float* Wk   = (const float*)d_in[8];
    const float* bk   = (const float*)d_in[9];
    const float* Wv   = (const float*)d_in[10];
    const float* bv   = (const float*)d_in[11];

    char* ws = (char*)d_ws;
    size_t off = 0;
    auto alloc = [&](size_t bytes) -> void* {
        void* p = ws + off;
        off = (off + bytes + 255) & ~(size_t)255;
        return p;
    };
    float* a0f   = (float*)alloc((size_t)NN * 128 * 4);
    float* a1f   = (float*)alloc((size_t)NN * 128 * 4);
    float* q2    = (float*)alloc((size_t)NN * 128 * 4);
    float* BigW  = (float*)alloc(128 * 384 * 4);
    float* B2    = (float*)alloc(128 * 256 * 4);
    float* bqk   = (float*)alloc(128 * 4);
    float* wvecs = (float*)alloc(644 * 4);
    float* NS    = (float*)alloc((size_t)NN * 4 * 4);
    float* TT    = (float*)alloc((size_t)NN * 4 * 4);
    float* selfy = (float*)alloc((size_t)NN * 4);
    float* y     = (float*)alloc((size_t)NN * 4);
    u32* key     = (u32*)alloc((size_t)NN * 4);
    u64* S       = (u64*)alloc((size_t)NN * 8);
    u32* rnk     = (u32*)alloc((size_t)NN * 4);
    u32* selj    = (u32*)alloc((size_t)KSEL * 4);
    u32* bs      = (u32*)alloc(256 * 4);
    u32* bo      = (u32*)alloc(256 * 4);
    u32* P       = (u32*)alloc(65537 * 4);
    size_t zstart = off;
    float* acc = (float*)alloc((size_t)NN * 4 * 4);
    u32* hist  = (u32*)alloc(65536 * 4);
    u32* cnt   = (u32*)alloc(65536 * 4);
    size_t zend = off;
    (void)ws_size; (void)n_in; (void)in_sizes; (void)out_size;

    hipMemsetAsync(ws + zstart, 0, zend - zstart, stream);

    k_wqk<<<128, 128, 0, stream>>>(Wq, Wk, bq, BigW, bqk);
    k_prep<<<(128 * 256 * 2 + 641 + 255) / 256, 256, 0, stream>>>(Wb, Wq, bq, bk, Wv, BigW, B2, wvecs);
    k_gemm1<<<dim3((NN + 127) / 128, 3), 256, 0, stream>>>(h, BigW, bqk, q2, a0f, a1f);
    k_gemm2<<<dim3((NN + 127) / 128, 2), 256, 0, stream>>>(q2, B2, h, TT);
    k_scal<<<(NN * 64 + 255) / 256, 256, 0, stream>>>(h, wvecs, coeff, bv, NS, TT, selfy);
    k_edge<<<(NE * 64 + 255) / 256, 256, 0, stream>>>(a0f, a1f, q2, src, dstp, etype, NS, TT, coeff, bv, acc);
    int nb = (NN + 255) / 256;
    k_y<<<nb, 256, 0, stream>>>(acc, selfy, y, key, hist);
    k_scan<<<1, 1024, 0, stream>>>(hist, P);
    k_scatter<<<nb, 256, 0, stream>>>(key, P, cnt, S);
    k_rank<<<nb, 256, 0, stream>>>(key, P, S, rnk);
    k_bsum<<<nb, 256, 0, stream>>>(rnk, bs);
    k_bscan<<<1, 64, 0, stream>>>(bs, bo, nb);
    float* out = (float*)d_out;
    k_select<<<nb, 256, 0, stream>>>(rnk, bo, selj, out + (size_t)KSEL * 128);
    k_rows<<<(KSEL + 1) / 2, 256, 0, stream>>>(selj, h, y, out);
}

// Round 7
// 429.081 us; speedup vs baseline: 1.5069x; 1.5069x over previous
//
#include <hip/hip_runtime.h>
#include <hip/hip_bf16.h>
#include <math.h>

#define NN 50000
#define NE 500000
#define KSEL 25000

typedef unsigned int u32;
typedef unsigned long long u64;
typedef short bf16x8 __attribute__((ext_vector_type(8)));   // 8 bf16 raw bits (4 VGPRs)
typedef float f32x4 __attribute__((ext_vector_type(4)));

__device__ __forceinline__ unsigned short f2bf(float f) {   // RNE
    u32 u = __float_as_uint(f);
    u32 r = (u + 0x7fffu + ((u >> 16) & 1u)) >> 16;
    return (unsigned short)r;
}
// dot of two u32s each holding 2 bf16 (lo = even elem, hi = odd elem)
__device__ __forceinline__ float dpair(u32 a, u32 q) {
    float al = __uint_as_float(a << 16), ah = __uint_as_float(a & 0xffff0000u);
    float ql = __uint_as_float(q << 16), qh = __uint_as_float(q & 0xffff0000u);
    return al * ql + ah * qh;
}

// ---------------- precompute ----------------

// h (f32) -> hb (bf16 bits)
__global__ __launch_bounds__(256) void k_cast(const float* __restrict__ h, unsigned short* __restrict__ hb) {
    int i = blockIdx.x * 256 + threadIdx.x;   // 1.6M threads, 4 elems each
    float4 v = *(const float4*)(h + (size_t)i * 4);
    ushort4 o;
    o.x = f2bf(v.x); o.y = f2bf(v.y); o.z = f2bf(v.z); o.w = f2bf(v.w);
    *(ushort4*)(hb + (size_t)i * 4) = o;
}

// panel0 of Gt: Gt[m][k] = Wqk[k][m] = sum_c Wq[c,k]*Wk[c,m]; bqk[m] = sum_c bq[c]*Wk[c,m]
__global__ __launch_bounds__(128) void k_wqk(const float* __restrict__ Wq, const float* __restrict__ Wk,
                                             const float* __restrict__ bq,
                                             unsigned short* __restrict__ Gt, float* __restrict__ bqk) {
    int k = blockIdx.x;   // 0..127
    int m = threadIdx.x;  // 0..127
    float acc = 0.f;
    for (int c = 0; c < 128; ++c) acc += Wq[c * 128 + k] * Wk[c * 128 + m];
    Gt[(size_t)m * 128 + k] = f2bf(acc);
    if (k == 0) {
        float b = 0.f;
        for (int c = 0; c < 128; ++c) b += bq[c] * Wk[c * 128 + m];
        bqk[m] = b;
    }
}

// Gt panels 1-4 (W0a,W1a,W0b,W1b transposed) + wvecs
// wvecs: wa0[0:128] wa1[128:256] wb0[256:384] wb1[384:512] wkn[512:640] bkbq[640]
__global__ void k_prep(const float* __restrict__ Wb, const float* __restrict__ Wq,
                       const float* __restrict__ bq, const float* __restrict__ bk,
                       const float* __restrict__ Wv,
                       unsigned short* __restrict__ Gt, float* __restrict__ wvecs) {
    int idx = blockIdx.x * blockDim.x + threadIdx.x;
    if (idx < 65536) {
        int p = idx >> 14, rem = idx & 16383;
        int c = rem >> 7, k = rem & 127;
        float v;
        if (p == 0)      v = Wb[k * 128 + c];                    // W0a -> panel1
        else if (p == 1) v = Wb[32768 + k * 128 + c];            // W1a -> panel2
        else if (p == 2) v = Wb[16384 + k * 128 + c];            // W0b -> panel3
        else             v = Wb[49152 + k * 128 + c];            // W1b -> panel4
        Gt[(size_t)((p + 1) * 128 + c) * 128 + k] = f2bf(v);
    } else {
        int i = idx - 65536;
        if (i < 128)      { float s = 0; for (int m = 0; m < 128; ++m) s += Wb[i * 128 + m] * Wv[m]; wvecs[i] = s; }
        else if (i < 256) { int j = i - 128; float s = 0; for (int m = 0; m < 128; ++m) s += Wb[32768 + j * 128 + m] * Wv[m]; wvecs[i] = s; }
        else if (i < 384) { int j = i - 256; float s = 0; for (int m = 0; m < 128; ++m) s += Wb[(128 + j) * 128 + m] * Wv[m]; wvecs[i] = s; }
        else if (i < 512) { int j = i - 384; float s = 0; for (int m = 0; m < 128; ++m) s += Wb[32768 + (128 + j) * 128 + m] * Wv[m]; wvecs[i] = s; }
        else if (i < 640) { int j = i - 512; float s = 0; for (int c = 0; c < 128; ++c) s += bk[c] * Wq[c * 128 + j]; wvecs[i] = s; }
        else if (i == 640) { float s = 0; for (int c = 0; c < 128; ++c) s += bk[c] * bq[c]; wvecs[640] = s; }
    }
}

// ---------------- fused node GEMM: Y = hb @ G (128x640), bf16 MFMA, no LDS ----------------
// grid (391, 5 panels), 256 thr (4 waves). Wave w: rows [w*32, w*32+32), full 128-col panel.
// panel 0 -> q2b (+bqk), 1 -> a01b[:,0:128], 2 -> a01b[:,128:256], 3 -> w0b, 4 -> w1b
__global__ __launch_bounds__(256) void k_mfma(const unsigned short* __restrict__ hb,
                                              const unsigned short* __restrict__ Gt,
                                              const float* __restrict__ bqk,
                                              unsigned short* __restrict__ q2b,
                                              unsigned short* __restrict__ a01b,
                                              unsigned short* __restrict__ w0b,
                                              unsigned short* __restrict__ w1b) {
    int t = threadIdx.x;
    int w = t >> 6, l = t & 63;
    int lr = l & 15, lg = l >> 4;               // A: row=lr, k-group=lg ; C/D: col=lr, row-group=lg
    int mb = blockIdx.x * 128;
    int panel = blockIdx.y;
    int rowbase = mb + w * 32;

    bf16x8 afr[2][4];
#pragma unroll
    for (int rt = 0; rt < 2; ++rt)
#pragma unroll
        for (int kk = 0; kk < 4; ++kk) {
            int row = rowbase + rt * 16 + lr;
            if (row >= NN) row = NN - 1;        // clamp; stores are guarded
            afr[rt][kk] = *reinterpret_cast<const bf16x8*>(hb + (size_t)row * 128 + kk * 32 + lg * 8);
        }

    f32x4 acc[2][8];
#pragma unroll
    for (int rt = 0; rt < 2; ++rt)
#pragma unroll
        for (int ct = 0; ct < 8; ++ct) acc[rt][ct] = (f32x4){0.f, 0.f, 0.f, 0.f};

#pragma unroll
    for (int ct = 0; ct < 8; ++ct) {
#pragma unroll
        for (int kk = 0; kk < 4; ++kk) {
            int gcol = panel * 128 + ct * 16 + lr;
            bf16x8 bfr = *reinterpret_cast<const bf16x8*>(Gt + (size_t)gcol * 128 + kk * 32 + lg * 8);
            acc[0][ct] = __builtin_amdgcn_mfma_f32_16x16x32_bf16(afr[0][kk], bfr, acc[0][ct], 0, 0, 0);
            acc[1][ct] = __builtin_amdgcn_mfma_f32_16x16x32_bf16(afr[1][kk], bfr, acc[1][ct], 0, 0, 0);
        }
    }

#pragma unroll
    for (int rt = 0; rt < 2; ++rt)
#pragma unroll
        for (int ct = 0; ct < 8; ++ct)
#pragma unroll
            for (int r = 0; r < 4; ++r) {
                int row = rowbase + rt * 16 + lg * 4 + r;
                if (row >= NN) continue;
                int col = ct * 16 + lr;
                float v = acc[rt][ct][r];
                if (panel == 0) {
                    q2b[(size_t)row * 128 + col] = f2bf(v + bqk[col]);
                } else if (panel == 1) {
                    a01b[(size_t)row * 256 + col] = f2bf(v);
                } else if (panel == 2) {
                    a01b[(size_t)row * 256 + 128 + col] = f2bf(v);
                } else if (panel == 3) {
                    w0b[(size_t)row * 128 + col] = f2bf(v);
                } else {
                    w1b[(size_t)row * 128 + col] = f2bf(v);
                }
            }
}

// t0[n] = w0[n]·q2[n], t1[n] = w1[n]·q2[n]  (1 wave per node)
__global__ __launch_bounds__(256) void k_tdot(const unsigned short* __restrict__ q2b,
                                              const unsigned short* __restrict__ w0b,
                                              const unsigned short* __restrict__ w1b,
                                              float* __restrict__ TT) {
    int n = blockIdx.x * 4 + (threadIdx.x >> 6);
    int lane = threadIdx.x & 63;
    u32 qw = ((const u32*)(q2b + (size_t)n * 128))[lane];
    u32 w0 = ((const u32*)(w0b + (size_t)n * 128))[lane];
    u32 w1 = ((const u32*)(w1b + (size_t)n * 128))[lane];
    float t0 = dpair(w0, qw);
    float t1 = dpair(w1, qw);
    for (int off = 32; off; off >>= 1) {
        t0 += __shfl_xor(t0, off);
        t1 += __shfl_xor(t1, off);
    }
    if (lane == 0) {
        TT[(size_t)n * 4 + 0] = t0;
        TT[(size_t)n * 4 + 1] = t1;
    }
}

// per-node scalars: av0,av1,bv0,bv1 (NS), kn (TT.z), self_y  (f32 h, exact)
__global__ void k_scal(const float* __restrict__ h, const float* __restrict__ wvecs,
                       const float* __restrict__ coeff, const float* __restrict__ bvp,
                       float* __restrict__ NS, float* __restrict__ TT, float* __restrict__ selfy) {
    int gid = blockIdx.x * blockDim.x + threadIdx.x;
    int wid = gid >> 6, lane = gid & 63;
    if (wid >= NN) return;
    const float* hrow = h + (size_t)wid * 128;
    float2 hv = *(const float2*)(hrow + lane * 2);
    float2 w0 = *(const float2*)(wvecs + 0 + lane * 2);
    float2 w1 = *(const float2*)(wvecs + 128 + lane * 2);
    float2 w2 = *(const float2*)(wvecs + 256 + lane * 2);
    float2 w3 = *(const float2*)(wvecs + 384 + lane * 2);
    float2 w4 = *(const float2*)(wvecs + 512 + lane * 2);
    float p0 = hv.x * w0.x + hv.y * w0.y;
    float p1 = hv.x * w1.x + hv.y * w1.y;
    float p2 = hv.x * w2.x + hv.y * w2.y;
    float p3 = hv.x * w3.x + hv.y * w3.y;
    float p4 = hv.x * w4.x + hv.y * w4.y;
    for (int off = 32; off; off >>= 1) {
        p0 += __shfl_xor(p0, off);
        p1 += __shfl_xor(p1, off);
        p2 += __shfl_xor(p2, off);
        p3 += __shfl_xor(p3, off);
        p4 += __shfl_xor(p4, off);
    }
    if (lane == 0) {
        float kn = p4 + wvecs[640];
        float c40 = coeff[8], c41 = coeff[9], bv = bvp[0];
        NS[(size_t)wid * 4 + 0] = p0;
        NS[(size_t)wid * 4 + 1] = p1;
        NS[(size_t)wid * 4 + 2] = p2;
        NS[(size_t)wid * 4 + 3] = p3;
        TT[(size_t)wid * 4 + 2] = kn;
        selfy[wid] = c40 * (p0 + p2) + c41 * (p1 + p3) + bv;
    }
}

// ---------------- edge kernel: bf16, 2 edges/wave, 8-lane dot groups ----------------
__global__ __launch_bounds__(256) void k_edge(const unsigned short* __restrict__ a01b,
                                              const unsigned short* __restrict__ q2b,
                                              const int* __restrict__ src, const int* __restrict__ dst,
                                              const int* __restrict__ et,
                                              const float* __restrict__ NS, const float* __restrict__ TT,
                                              const float* __restrict__ coeff, const float* __restrict__ bvp,
                                              float* __restrict__ acc) {
    int tid = threadIdx.x;
    int e = blockIdx.x * 8 + (tid >> 5);        // 8 edges per 256-thr block (exact: NE/8 blocks)
    int lane = tid & 63;
    int l5 = tid & 31;
    int g = l5 >> 3, sub = l5 & 7;              // 4 dot groups of 8 lanes per edge
    int s = src[e], d = dst[e];
    int r1 = (g < 2) ? s : d;
    int r2 = (g < 2) ? d : s;
    const u32* ap = (const u32*)(a01b + (size_t)r1 * 256 + (g & 1) * 128) + sub * 8;
    const u32* qp = (const u32*)(q2b + (size_t)r2 * 128) + sub * 8;
    uint4 A0 = *(const uint4*)ap, A1 = *(const uint4*)(ap + 4);
    uint4 Q0 = *(const uint4*)qp, Q1 = *(const uint4*)(qp + 4);
    float p = dpair(A0.x, Q0.x) + dpair(A0.y, Q0.y) + dpair(A0.z, Q0.z) + dpair(A0.w, Q0.w) +
              dpair(A1.x, Q1.x) + dpair(A1.y, Q1.y) + dpair(A1.z, Q1.z) + dpair(A1.w, Q1.w);
    p += __shfl_xor(p, 4);
    p += __shfl_xor(p, 2);
    p += __shfl_xor(p, 1);
    float mate = __shfl(p, (lane + 8) & 63);    // lane0<-8 (d1 in), lane16<-24 (d1 out), +32 for edge B
    if ((l5 & 15) == 0) {
        bool outdir = (l5 == 16);
        int agg = outdir ? s : d;
        int oth = outdir ? d : s;
        int ety = et[e];
        float c0 = coeff[ety * 2], c1 = coeff[ety * 2 + 1];
        float4 tt = *(const float4*)(TT + (size_t)agg * 4);
        float4 nsO = *(const float4*)(NS + (size_t)oth * 4);
        float4 nsA = *(const float4*)(NS + (size_t)agg * 4);
        float raw = c0 * (p + tt.x) + c1 * (mate + tt.y) + tt.z;
        float xc = fminf(fmaxf(raw * 0.08838834764831845f, -10.f), 10.f);
        float sc = expf(xc);
        float nv = c0 * (nsO.x + nsA.z) + c1 * (nsO.y + nsA.w) + bvp[0];
        float* wacc = acc + (size_t)(outdir ? 2 : 0) * NN;
        float* zacc = acc + (size_t)(outdir ? 3 : 1) * NN;
        atomicAdd(&wacc[agg], sc * nv);
        atomicAdd(&zacc[agg], sc);
    }
}

// ---------------- y, key, ranking, selection, output ----------------

__global__ void k_y(const float* __restrict__ acc, const float* __restrict__ selfy,
                    float* __restrict__ y, u32* __restrict__ key, u32* __restrict__ hist) {
    int i = blockIdx.x * blockDim.x + threadIdx.x;
    if (i >= NN) return;
    float win = acc[i], zin = acc[NN + i], wout = acc[2 * NN + i], zout = acc[3 * NN + i];
    float v = win / (zin + 1e-6f) + wout / (zout + 1e-6f) + selfy[i];
    y[i] = v;
    u32 u = __float_as_uint(v);
    u32 m = (u32)((int)u >> 31) | 0x80000000u;
    u32 k = ~(u ^ m);  // ascending k == descending y
    key[i] = k;
    atomicAdd(&hist[k >> 16], 1u);
}

__global__ __launch_bounds__(1024) void k_scan(const u32* __restrict__ hist, u32* __restrict__ P) {
    __shared__ u32 wsum[16];
    __shared__ u32 woff[16];
    int t = threadIdx.x;
    int base = t * 64;
    u32 s = 0;
    for (int i = 0; i < 64; ++i) s += hist[base + i];
    u32 v = s;
    int lane = t & 63;
    for (int off = 1; off < 64; off <<= 1) {
        u32 n = __shfl_up(v, off);
        if (lane >= off) v += n;
    }
    int wid = t >> 6;
    if (lane == 63) wsum[wid] = v;
    __syncthreads();
    if (t == 0) {
        u32 r = 0;
        for (int w = 0; w < 16; ++w) { woff[w] = r; r += wsum[w]; }
    }
    __syncthreads();
    u32 excl = v - s + woff[wid];
    for (int i = 0; i < 64; ++i) { P[base + i] = excl; excl += hist[base + i]; }
    if (t == 1023) P[65536] = excl;
}

__global__ void k_scatter(const u32* __restrict__ key, const u32* __restrict__ P,
                          u32* __restrict__ cnt, u64* __restrict__ S) {
    int i = blockIdx.x * blockDim.x + threadIdx.x;
    if (i >= NN) return;
    u32 k = key[i];
    u32 b = k >> 16;
    u32 pos = P[b] + atomicAdd(&cnt[b], 1u);
    S[pos] = ((u64)k << 16) | (u32)i;
}

__global__ void k_rank(const u32* __restrict__ key, const u32* __restrict__ P,
                       const u64* __restrict__ S, u32* __restrict__ rnk) {
    int i = blockIdx.x * blockDim.x + threadIdx.x;
    if (i >= NN) return;
    u32 k = key[i];
    u32 b = k >> 16;
    u64 me = ((u64)k << 16) | (u32)i;
    u32 st = P[b], en = P[b + 1];
    u32 c = 0;
    for (u32 j = st; j < en; ++j) c += (S[j] < me) ? 1u : 0u;
    rnk[i] = st + c;
}

__global__ void k_bsum(const u32* __restrict__ rnk, u32* __restrict__ bs) {
    __shared__ u32 red[4];
    int i = blockIdx.x * 256 + threadIdx.x;
    u32 v = (i < NN && rnk[i] < KSEL) ? 1u : 0u;
    for (int off = 32; off; off >>= 1) v += __shfl_xor(v, off);
    int lane = threadIdx.x & 63, w = threadIdx.x >> 6;
    if (lane == 0) red[w] = v;
    __syncthreads();
    if (threadIdx.x == 0) bs[blockIdx.x] = red[0] + red[1] + red[2] + red[3];
}

__global__ void k_bscan(const u32* __restrict__ bs, u32* __restrict__ bo, int nb) {
    if (threadIdx.x == 0) {
        u32 r = 0;
        for (int i = 0; i < nb; ++i) { bo[i] = r; r += bs[i]; }
    }
}

__global__ void k_select(const u32* __restrict__ rnk, const u32* __restrict__ bo,
                         u32* __restrict__ selj, float* __restrict__ out_ids) {
    __shared__ u32 woff[4];
    int t = threadIdx.x;
    int i = blockIdx.x * 256 + t;
    u32 f = (i < NN && rnk[i] < KSEL) ? 1u : 0u;
    u32 v = f;
    int lane = t & 63;
    for (int off = 1; off < 64; off <<= 1) {
        u32 n = __shfl_up(v, off);
        if (lane >= off) v += n;
    }
    int w = t >> 6;
    if (lane == 63) woff[w] = v;
    __syncthreads();
    if (t == 0) {
        u32 r = 0;
        for (int k = 0; k < 4; ++k) { u32 x = woff[k]; woff[k] = r; r += x; }
    }
    __syncthreads();
    if (f) {
        u32 r = bo[blockIdx.x] + woff[w] + (v - f);
        selj[r] = rnk[i];
        out_ids[r] = (float)i;
    }
}

__global__ void k_rows(const u32* __restrict__ selj, const float* __restrict__ h,
                       const float* __restrict__ y, float* __restrict__ out) {
    int row = blockIdx.x * 2 + (threadIdx.x >> 7);
    int c = threadIdx.x & 127;
    if (row >= KSEL) return;
    u32 j = selj[row];
    float yv = y[j];
    float sig = 1.f / (1.f + expf(-yv));
    float v = h[(size_t)j * 128 + c] * sig;
    out[(size_t)row * 128 + c] = v;
}

// ---------------- launcher ----------------

extern "C" void kernel_launch(void* const* d_in, const int* in_sizes, int n_in,
                              void* d_out, int out_size, void* d_ws, size_t ws_size,
                              hipStream_t stream) {
    const float* h    = (const float*)d_in[0];
    const int* src    = (const int*)d_in[1];
    const int* dstp   = (const int*)d_in[2];
    const int* etype  = (const int*)d_in[3];
    const float* Wb   = (const float*)d_in[4];
    const float* coeff = (const float*)d_in[5];
    const float* Wq   = (const float*)d_in[6];
    const float* bq   = (const float*)d_in[7];
    const float* Wk   = (const float*)d_in[8];
    const float* bk   = (const float*)d_in[9];
    const float* Wv   = (const float*)d_in[10];
    const float* bv   = (const float*)d_in[11];

    char* ws = (char*)d_ws;
    size_t off = 0;
    auto alloc = [&](size_t bytes) -> void* {
        void* p = ws + off;
        off = (off + bytes + 255) & ~(size_t)255;
        return p;
    };
    unsigned short* hb   = (unsigned short*)alloc((size_t)NN * 128 * 2);
    unsigned short* Gt   = (unsigned short*)alloc((size_t)640 * 128 * 2);
    unsigned short* q2b  = (unsigned short*)alloc((size_t)NN * 128 * 2);
    unsigned short* a01b = (unsigned short*)alloc((size_t)NN * 256 * 2);
    unsigned short* w0b  = (unsigned short*)alloc((size_t)NN * 128 * 2);
    unsigned short* w1b  = (unsigned short*)alloc((size_t)NN * 128 * 2);
    float* bqk   = (float*)alloc(128 * 4);
    float* wvecs = (float*)alloc(644 * 4);
    float* NS    = (float*)alloc((size_t)NN * 4 * 4);
    float* TT    = (float*)alloc((size_t)NN * 4 * 4);
    float* selfy = (float*)alloc((size_t)NN * 4);
    float* y     = (float*)alloc((size_t)NN * 4);
    u32* key     = (u32*)alloc((size_t)NN * 4);
    u64* S       = (u64*)alloc((size_t)NN * 8);
    u32* rnk     = (u32*)alloc((size_t)NN * 4);
    u32* selj    = (u32*)alloc((size_t)KSEL * 4);
    u32* bs      = (u32*)alloc(256 * 4);
    u32* bo      = (u32*)alloc(256 * 4);
    u32* P       = (u32*)alloc(65537 * 4);
    size_t zstart = off;
    float* acc = (float*)alloc((size_t)NN * 4 * 4);
    u32* hist  = (u32*)alloc(65536 * 4);
    u32* cnt   = (u32*)alloc(65536 * 4);
    size_t zend = off;
    (void)ws_size; (void)n_in; (void)in_sizes; (void)out_size;

    hipMemsetAsync(ws + zstart, 0, zend - zstart, stream);

    k_cast<<<(NN * 128 / 4 + 255) / 256, 256, 0, stream>>>(h, hb);
    k_wqk<<<128, 128, 0, stream>>>(Wq, Wk, bq, Gt, bqk);
    k_prep<<<(65536 + 641 + 255) / 256, 256, 0, stream>>>(Wb, Wq, bq, bk, Wv, Gt, wvecs);
    k_mfma<<<dim3((NN + 127) / 128, 5), 256, 0, stream>>>(hb, Gt, bqk, q2b, a01b, w0b, w1b);
    k_tdot<<<(NN + 3) / 4, 256, 0, stream>>>(q2b, w0b, w1b, TT);
    k_scal<<<(NN * 64 + 255) / 256, 256, 0, stream>>>(h, wvecs, coeff, bv, NS, TT, selfy);
    k_edge<<<NE / 8, 256, 0, stream>>>(a01b, q2b, src, dstp, etype, NS, TT, coeff, bv, acc);
    int nb = (NN + 255) / 256;
    k_y<<<nb, 256, 0, stream>>>(acc, selfy, y, key, hist);
    k_scan<<<1, 1024, 0, stream>>>(hist, P);
    k_scatter<<<nb, 256, 0, stream>>>(key, P, cnt, S);
    k_rank<<<nb, 256, 0, stream>>>(key, P, S, rnk);
    k_bsum<<<nb, 256, 0, stream>>>(rnk, bs);
    k_bscan<<<1, 64, 0, stream>>>(bs, bo, nb);
    float* out = (float*)d_out;
    k_select<<<nb, 256, 0, stream>>>(rnk, bo, selj, out + (size_t)KSEL * 128);
    k_rows<<<(KSEL + 1) / 2, 256, 0, stream>>>(selj, h, y, out);
}